// Round 7
// baseline (750.452 us; speedup 1.0000x reference)
//
#include <hip/hip_runtime.h>

// ---------------------------------------------------------------------------
// GCN 3-layer forward on MI355X — Round 11: nontemporal gather, compile-fixed.
// R10 failed to compile: __builtin_nontemporal_load rejects HIP_vector_type
// (ushort4 is a class). Fix: clang ext_vector alias us4 (same 8B layout).
// Theory unchanged: gather rate pinned at ~26.6 GB/s/CU regardless of
// wave/instr parallelism (R7/R9) => per-CU L1 miss-tracking limit; nt loads
// bypass L1 into the deeper TCC queues. Gather rows have zero L1 value.
// Also kept from R10: R8-shape gather (8B/lane, readlane), merged weight cast.
// GEMM (fp16 MFMA + XCD pairing), scan, atomic-free CSR, folded norm kept.
// ---------------------------------------------------------------------------

constexpr int DIN = 128;
constexpr int DH  = 256;

typedef _Float16 f16x8 __attribute__((ext_vector_type(8)));
typedef float    f32x4 __attribute__((ext_vector_type(4)));
typedef unsigned short us4 __attribute__((ext_vector_type(4)));

__device__ __forceinline__ float h2f(unsigned short u) {
    _Float16 h;
    __builtin_memcpy(&h, &u, 2);
    return (float)h;
}
__device__ __forceinline__ unsigned short f2h(float f) {
    _Float16 h = (_Float16)f;
    unsigned short u;
    __builtin_memcpy(&u, &h, 2);
    return u;
}

__global__ void zero_int_kernel(int* __restrict__ p, int n) {
    int i = blockIdx.x * blockDim.x + threadIdx.x;
    if (i < n) p[i] = 0;
}

// Degree count x4; atomic return value = within-node slot -> seq[e].
__global__ void count_deg_kernel(const int* __restrict__ col, int E,
                                 int* __restrict__ deg, int* __restrict__ seq) {
    int i = blockIdx.x * blockDim.x + threadIdx.x;
    int base = i * 4;
    if (base >= E) return;
    if (base + 4 <= E && (((size_t)col & 15) == 0)) {
        int4 c = *(const int4*)(col + base);
        int4 s;
        s.x = atomicAdd(&deg[c.x], 1);
        s.y = atomicAdd(&deg[c.y], 1);
        s.z = atomicAdd(&deg[c.z], 1);
        s.w = atomicAdd(&deg[c.w], 1);
        *(int4*)(seq + base) = s;
    } else {
        for (int e = base; e < E && e < base + 4; ++e)
            seq[e] = atomicAdd(&deg[col[e]], 1);
    }
}

// ---- 3-phase multi-block exclusive scan over deg[0..N) -> rowptr[0..N] ----
__global__ __launch_bounds__(256) void scan_p1_kernel(const int* __restrict__ deg,
                                                      int* __restrict__ bsum, int N) {
    int t = threadIdx.x;
    int base = blockIdx.x * 1024 + t * 4;
    int s = 0;
    #pragma unroll
    for (int k = 0; k < 4; k++) { int i = base + k; if (i < N) s += deg[i]; }
    __shared__ int red[256];
    red[t] = s;
    __syncthreads();
    for (int off = 128; off > 0; off >>= 1) {
        if (t < off) red[t] += red[t + off];
        __syncthreads();
    }
    if (t == 0) bsum[blockIdx.x] = red[0];
}

__global__ __launch_bounds__(1024) void scan_p2_kernel(int* __restrict__ bsum, int nb) {
    __shared__ int sums[1024];
    int t = threadIdx.x;
    int chunk = (nb + 1023) / 1024;
    int s0 = t * chunk, s1 = min(nb, s0 + chunk);
    int local = 0;
    for (int i = s0; i < s1; i++) local += bsum[i];
    sums[t] = local;
    __syncthreads();
    for (int off = 1; off < 1024; off <<= 1) {
        int v = (t >= off) ? sums[t - off] : 0;
        __syncthreads();
        sums[t] += v;
        __syncthreads();
    }
    int prefix = (t == 0) ? 0 : sums[t - 1];
    for (int i = s0; i < s1; i++) { int v = bsum[i]; bsum[i] = prefix; prefix += v; }
}

// Phase 3: block-local exclusive scan + bsum[b] offset -> rowptr.
// Fused: dinv[i] = 1/sqrt(deg[i]+1).
__global__ __launch_bounds__(256) void scan_p3_kernel(const int* __restrict__ deg,
                                                      const int* __restrict__ bsum,
                                                      int* __restrict__ rowptr,
                                                      float* __restrict__ dinv,
                                                      int N, int E) {
    int t = threadIdx.x;
    int base = blockIdx.x * 1024 + t * 4;
    int v[4];
    int s = 0;
    #pragma unroll
    for (int k = 0; k < 4; k++) {
        int i = base + k;
        v[k] = (i < N) ? deg[i] : 0;
        s += v[k];
    }
    __shared__ int sums[256];
    sums[t] = s;
    __syncthreads();
    for (int off = 1; off < 256; off <<= 1) {
        int u = (t >= off) ? sums[t - off] : 0;
        __syncthreads();
        sums[t] += u;
        __syncthreads();
    }
    int prefix = bsum[blockIdx.x] + ((t == 0) ? 0 : sums[t - 1]);
    #pragma unroll
    for (int k = 0; k < 4; k++) {
        int i = base + k;
        if (i < N) {
            rowptr[i] = prefix;
            dinv[i] = 1.0f / sqrtf((float)(v[k] + 1));
        }
        prefix += v[k];
    }
    if (blockIdx.x == 0 && t == 0) rowptr[N] = E;
}

// Atomic-free CSR fill x4: pos = rowptr[col] + seq.
__global__ void fill_csr_kernel(const int* __restrict__ row, const int* __restrict__ col,
                                const int* __restrict__ seq, const int* __restrict__ rowptr,
                                int* __restrict__ csr_src, int E) {
    int i = blockIdx.x * blockDim.x + threadIdx.x;
    int base = i * 4;
    if (base >= E) return;
    if (base + 4 <= E && (((size_t)col & 15) == 0)) {
        int4 c = *(const int4*)(col + base);
        int4 s = *(const int4*)(seq + base);
        int4 r = *(const int4*)(row + base);
        csr_src[rowptr[c.x] + s.x] = r.x;
        csr_src[rowptr[c.y] + s.y] = r.y;
        csr_src[rowptr[c.z] + s.z] = r.z;
        csr_src[rowptr[c.w] + s.w] = r.w;
    } else {
        for (int e = base; e < E && e < base + 4; ++e)
            csr_src[rowptr[col[e]] + seq[e]] = row[e];
    }
}

// x~ = dinv[row] * x, fp16. Row of elem group i (4 fp32) = i / (DIN/4).
__global__ void cast_f16_scaled_kernel(const float4* __restrict__ in,
                                       const float* __restrict__ dinv,
                                       ushort4* __restrict__ out, int n4) {
    int i = blockIdx.x * blockDim.x + threadIdx.x;
    if (i >= n4) return;
    float s = dinv[i >> 5];                  // DIN/4 = 32 groups per row
    float4 v = in[i];
    ushort4 o;
    o.x = f2h(v.x * s); o.y = f2h(v.y * s); o.z = f2h(v.z * s); o.w = f2h(v.w * s);
    out[i] = o;
}

// All three weight matrices -> fp16 in one launch.
// W1: 8192 float4 groups, W2/W3: 16384 each (total 40960).
__global__ void cast_weights_kernel(const float4* __restrict__ W1,
                                    const float4* __restrict__ W2,
                                    const float4* __restrict__ W3,
                                    ushort4* __restrict__ w1h,
                                    ushort4* __restrict__ w2h,
                                    ushort4* __restrict__ w3h) {
    int i = blockIdx.x * blockDim.x + threadIdx.x;
    const float4* src; ushort4* dst; int j = i;
    if (j < 8192)       { src = W1; dst = w1h; }
    else if (j < 24576) { src = W2; dst = w2h; j -= 8192; }
    else if (j < 40960) { src = W3; dst = w3h; j -= 24576; }
    else return;
    float4 v = src[j];
    ushort4 o;
    o.x = f2h(v.x); o.y = f2h(v.y); o.z = f2h(v.z); o.w = f2h(v.w);
    dst[j] = o;
}

// One L-lane group per node; lane handles 4 fp16 elems (8B load). L = D/4.
// in: PRE-SCALED fp16 rows; out[n] = f2h(dinv[n] * (sum + self)).
// Row loads are NONTEMPORAL (bypass L1: gather rows have no L1 value; the
// per-CU L1 miss-tracking limit is the suspected 26.6 GB/s/CU cap).
template<int D>
__global__ __launch_bounds__(256) void agg_gather_f16_kernel(const int* __restrict__ rowptr,
                                                             const int* __restrict__ csr_src,
                                                             const float* __restrict__ dinv,
                                                             const us4* __restrict__ in,
                                                             us4* __restrict__ out, int N) {
    constexpr int L = D / 4;                 // 64 (D=256) or 32 (D=128)
    constexpr int GPB = 256 / L;
    int n = blockIdx.x * GPB + threadIdx.x / L;
    if (n >= N) return;
    int lane = threadIdx.x % L;

    us4 sv = __builtin_nontemporal_load(&in[(size_t)n * L + lane]);
    float4 acc = make_float4(h2f(sv.x), h2f(sv.y), h2f(sv.z), h2f(sv.w));

    int start = rowptr[n], end = rowptr[n + 1];
    for (int j0 = start; j0 < end; j0 += L) {
        int nb = end - j0; if (nb > L) nb = L;
        int src = (lane < nb) ? csr_src[j0 + lane] : 0;

        int t = 0;
        for (; t + 8 <= nb; t += 8) {
            int rr[8];
            #pragma unroll
            for (int u = 0; u < 8; ++u) {
                if constexpr (L == 64) rr[u] = __builtin_amdgcn_readlane(src, t + u);
                else                   rr[u] = __shfl(src, t + u, L);
            }
            us4 vv[8];
            #pragma unroll
            for (int u = 0; u < 8; ++u)
                vv[u] = __builtin_nontemporal_load(&in[(size_t)rr[u] * L + lane]);
            #pragma unroll
            for (int u = 0; u < 8; ++u) {
                acc.x += h2f(vv[u].x);
                acc.y += h2f(vv[u].y);
                acc.z += h2f(vv[u].z);
                acc.w += h2f(vv[u].w);
            }
        }
        for (; t < nb; ++t) {
            int r;
            if constexpr (L == 64) r = __builtin_amdgcn_readlane(src, t);
            else                   r = __shfl(src, t, L);
            us4 v = __builtin_nontemporal_load(&in[(size_t)r * L + lane]);
            acc.x += h2f(v.x); acc.y += h2f(v.y);
            acc.z += h2f(v.z); acc.w += h2f(v.w);
        }
    }
    float s = dinv[n];
    us4 o;
    o.x = f2h(acc.x * s); o.y = f2h(acc.y * s); o.z = f2h(acc.z * s); o.w = f2h(acc.w * s);
    out[(size_t)n * L + lane] = o;
}

// C[n][m] = sum_k A[n][k]*W[m][k]; A:[N,K] fp16, W:[256,K] fp16 (pre-cast).
// MFMA f16, fp32 accum. 128x128 tile, BK=64, 4 waves (2x2), 64x64 per wave.
// 1D grid, XCD-pairing decode: hw blocks 16g+r and 16g+r+8 (same XCD under
// round-robin) share cx -> second A-tile read hits that XCD's L2.
// SCALE: multiply output row by dinv[row] before fp16 store (h~ = dinv*relu).
template<int K, bool RELU, bool SCALE, typename OT>
__global__ __launch_bounds__(256) void gemm_nt_mfma_kernel(const unsigned short* __restrict__ A,
                                                           const unsigned short* __restrict__ Wh,
                                                           OT* __restrict__ C,
                                                           const float* __restrict__ dinv, int N) {
    __shared__ __align__(16) unsigned short As[128 * 64];
    __shared__ __align__(16) unsigned short Ws[128 * 64];
    int tid  = threadIdx.x;
    int lane = tid & 63;
    int wave = tid >> 6;
    int wr = wave >> 1, wc = wave & 1;       // wave grid 2x2

    // ---- XCD-pairing block decode
    int nwgx = (N + 127) / 128;
    int T = (2 * nwgx) & ~15;
    int b = blockIdx.x;
    int cx, cy;
    if (b < T) { cx = (b >> 4) * 8 + (b & 7); cy = (b >> 3) & 1; }
    else       { int rem = b - T; cx = (T >> 1) + (rem >> 1); cy = rem & 1; }
    int m0 = cx * 128;                       // output rows (nodes)
    int c0 = cy * 128;                       // output cols (0 or 128)

    f32x4 acc[4][4];
    #pragma unroll
    for (int i = 0; i < 4; i++)
        #pragma unroll
        for (int j = 0; j < 4; j++)
            #pragma unroll
            for (int r = 0; r < 4; r++) acc[i][j][r] = 0.0f;

    int srow  = tid >> 3;                    // 0..31: staging row within pass
    int sslot = tid & 7;                     // 16B slot within row (8 slots = 64 fp16)

    for (int k0 = 0; k0 < K; k0 += 64) {
        // ---- stage A[m0..m0+127][k0..k0+63] and W[c0..c0+127][k0..k0+63]
        #pragma unroll
        for (int q = 0; q < 4; ++q) {
            int row = q * 32 + srow;
            int byteoff = row * 128 + ((sslot ^ (row & 7)) << 4);
            int gr = m0 + row;
            if (gr >= N) gr = N - 1;         // clamp: tail rows computed, never stored
            f16x8 va = *(const f16x8*)(A + (size_t)gr * K + k0 + sslot * 8);
            *(f16x8*)((char*)As + byteoff) = va;
            int gw = c0 + row;               // always < 256
            f16x8 vw = *(const f16x8*)(Wh + (size_t)gw * K + k0 + sslot * 8);
            *(f16x8*)((char*)Ws + byteoff) = vw;
        }
        __syncthreads();

        // ---- 2 x K=32 MFMA steps over this BK=64 tile
        #pragma unroll
        for (int kk = 0; kk < 2; ++kk) {
            int slot = kk * 4 + (lane >> 4);
            f16x8 a[4], bfr[4];
            #pragma unroll
            for (int i = 0; i < 4; i++) {
                int row = wr * 64 + i * 16 + (lane & 15);
                a[i] = *(const f16x8*)((const char*)As + row * 128 + ((slot ^ (row & 7)) << 4));
            }
            #pragma unroll
            for (int j = 0; j < 4; j++) {
                int row = wc * 64 + j * 16 + (lane & 15);
                bfr[j] = *(const f16x8*)((const char*)Ws + row * 128 + ((slot ^ (row & 7)) << 4));
            }
            #pragma unroll
            for (int i = 0; i < 4; i++)
                #pragma unroll
                for (int j = 0; j < 4; j++)
                    acc[i][j] = __builtin_amdgcn_mfma_f32_16x16x32_f16(a[i], bfr[j], acc[i][j], 0, 0, 0);
        }
        __syncthreads();
    }

    // ---- epilogue: D lane map (verified m89): col = lane&15, row = (lane>>4)*4 + r
    int r4 = (lane >> 4) * 4;
    int cn = lane & 15;
    #pragma unroll
    for (int i = 0; i < 4; i++) {
        #pragma unroll
        for (int r = 0; r < 4; r++) {
            int g_r = m0 + wr * 64 + i * 16 + r4 + r;
            if (g_r >= N) continue;
            float dv = SCALE ? dinv[g_r] : 1.0f;
            #pragma unroll
            for (int j = 0; j < 4; j++) {
                float v = acc[i][j][r];
                if (RELU) v = fmaxf(v, 0.f);
                if (SCALE) v *= dv;
                int col = c0 + wc * 64 + j * 16 + cn;
                if constexpr (sizeof(OT) == 4) {
                    ((float*)C)[(size_t)g_r * DH + col] = v;
                } else {
                    ((unsigned short*)C)[(size_t)g_r * DH + col] = f2h(v);
                }
            }
        }
    }
}

extern "C" void kernel_launch(void* const* d_in, const int* in_sizes, int n_in,
                              void* d_out, int out_size, void* d_ws, size_t ws_size,
                              hipStream_t stream) {
    const float* x  = (const float*)d_in[0];
    const int*   ei = (const int*)d_in[1];
    const float* W1 = (const float*)d_in[2];
    const float* W2 = (const float*)d_in[3];
    const float* W3 = (const float*)d_in[4];
    float* out = (float*)d_out;

    int N = in_sizes[0] / DIN;
    int E = in_sizes[1] / 2;
    const int* row = ei;         // sources
    const int* col = ei + E;     // targets (aggregation)

    char* ws = (char*)d_ws;
    int*   deg     = (int*)ws;                      // N ints
    float* dinv    = (float*)(ws + 400000);         // N floats
    int*   rowptr  = (int*)(ws + 800000);           // N+1 ints
    int*   csr_src = (int*)(ws + 1200016);          // E ints
    int*   seq     = (int*)(ws + 7600016);          // E ints
    unsigned short* bufA = (unsigned short*)(ws + 14000128);  // N*256 fp16 agg out (A operand)
    unsigned short* w1h  = (unsigned short*)(ws + 65200128);  // 256*128 fp16
    unsigned short* w2h  = (unsigned short*)(ws + 65265664);  // 256*256 fp16
    unsigned short* w3h  = (unsigned short*)(ws + 65396736);  // 256*256 fp16
    int*   bsum    = (int*)(ws + 65527808);         // ~(N/1024)+1 ints, scan block sums

    // fp16 staging for gather inputs lives inside d_out (dead/overwritten):
    // x~ (N*128, 25.6MB) is dead before GEMM1 writes h~ (N*256 fp16, 51.2MB)
    // over it; GEMM3 fully overwrites d_out with the fp32 result.
    unsigned short* hb = (unsigned short*)d_out;

    dim3 b256(256);
    int nb = (N + 1023) / 1024;                     // scan blocks (98 @ N=100K)

    // CSR build: deg+seq -> rowptr (3-phase scan, dinv fused) -> atomic-free fill
    zero_int_kernel<<<dim3((N + 255) / 256), b256, 0, stream>>>(deg, N);
    count_deg_kernel<<<dim3(((E + 3) / 4 + 255) / 256), b256, 0, stream>>>(col, E, deg, seq);
    scan_p1_kernel<<<dim3(nb), b256, 0, stream>>>(deg, bsum, N);
    scan_p2_kernel<<<dim3(1), dim3(1024), 0, stream>>>(bsum, nb);
    scan_p3_kernel<<<dim3(nb), b256, 0, stream>>>(deg, bsum, rowptr, dinv, N, E);
    fill_csr_kernel<<<dim3(((E + 3) / 4 + 255) / 256), b256, 0, stream>>>(
        row, col, seq, rowptr, csr_src, E);

    // x~ = dinv*x (needs dinv from scan_p3); all weights in one launch
    cast_f16_scaled_kernel<<<dim3((N * (DIN / 4) + 255) / 256), b256, 0, stream>>>(
        (const float4*)x, dinv, (ushort4*)hb, N * (DIN / 4));
    cast_weights_kernel<<<dim3(160), b256, 0, stream>>>(
        (const float4*)W1, (const float4*)W2, (const float4*)W3,
        (ushort4*)w1h, (ushort4*)w2h, (ushort4*)w3h);

    int nwg = 2 * ((N + 127) / 128);

    // ---- Layer 1: s = dinv*(sum x~); h1~ = dinv*f16(relu(s @ W1^T))
    agg_gather_f16_kernel<DIN><<<dim3((N + 7) / 8), b256, 0, stream>>>(
        rowptr, csr_src, dinv, (const us4*)hb, (us4*)bufA, N);
    gemm_nt_mfma_kernel<DIN, true, true, unsigned short><<<dim3(nwg), b256, 0, stream>>>(
        bufA, w1h, hb, dinv, N);

    // ---- Layer 2: s = dinv*(sum h1~); h2~ = dinv*f16(relu(s @ W2^T))
    agg_gather_f16_kernel<DH><<<dim3((N + 3) / 4), b256, 0, stream>>>(
        rowptr, csr_src, dinv, (const us4*)hb, (us4*)bufA, N);
    gemm_nt_mfma_kernel<DH, true, true, unsigned short><<<dim3(nwg), b256, 0, stream>>>(
        bufA, w2h, hb, dinv, N);

    // ---- Layer 3: s = dinv*(sum h2~); out = s @ W3^T (fp32, full overwrite)
    agg_gather_f16_kernel<DH><<<dim3((N + 3) / 4), b256, 0, stream>>>(
        rowptr, csr_src, dinv, (const us4*)hb, (us4*)bufA, N);
    gemm_nt_mfma_kernel<DH, false, false, float><<<dim3(nwg), b256, 0, stream>>>(
        bufA, w3h, out, dinv, N);
}

// Round 8
// 633.682 us; speedup vs baseline: 1.1843x; 1.1843x over previous
//
#include <hip/hip_runtime.h>

// ---------------------------------------------------------------------------
// GCN 3-layer forward on MI355X — Round 12: XCD-partitioned gather.
// R11 post-mortem: nt bypass REGRESSED (117.5->170us, FETCH up) -> gather BW
// = fixed in-flight bytes / avg latency (per-CU MSHR cap); L1 hits were
// lowering avg latency. Only remaining lever: raise cache-hit fraction.
// Fix: split gather by feature-dim halves, half = blockIdx.x & 1. Under
// round-robin block->XCD, even blocks (XCD 0,2,4,6) touch dims [0,D/2),
// odd (XCD 1,3,5,7) touch [D/2,D): each 25.6MB half-array cached by 16MB
// of L2 instead of all XCDs caching the full 51MB -> hit rate up, avg
// latency down, BW up. Same request volume, same per-element accumulation
// order (absmax identical). Memory ops identical to R8 (plain loads).
// GEMM (fp16 MFMA + XCD pairing), scan, atomic-free CSR, folded norm kept.
// ---------------------------------------------------------------------------

constexpr int DIN = 128;
constexpr int DH  = 256;

typedef _Float16 f16x8 __attribute__((ext_vector_type(8)));
typedef float    f32x4 __attribute__((ext_vector_type(4)));
typedef unsigned short us4 __attribute__((ext_vector_type(4)));

__device__ __forceinline__ float h2f(unsigned short u) {
    _Float16 h;
    __builtin_memcpy(&h, &u, 2);
    return (float)h;
}
__device__ __forceinline__ unsigned short f2h(float f) {
    _Float16 h = (_Float16)f;
    unsigned short u;
    __builtin_memcpy(&u, &h, 2);
    return u;
}

__global__ void zero_int_kernel(int* __restrict__ p, int n) {
    int i = blockIdx.x * blockDim.x + threadIdx.x;
    if (i < n) p[i] = 0;
}

// Degree count x4; atomic return value = within-node slot -> seq[e].
__global__ void count_deg_kernel(const int* __restrict__ col, int E,
                                 int* __restrict__ deg, int* __restrict__ seq) {
    int i = blockIdx.x * blockDim.x + threadIdx.x;
    int base = i * 4;
    if (base >= E) return;
    if (base + 4 <= E && (((size_t)col & 15) == 0)) {
        int4 c = *(const int4*)(col + base);
        int4 s;
        s.x = atomicAdd(&deg[c.x], 1);
        s.y = atomicAdd(&deg[c.y], 1);
        s.z = atomicAdd(&deg[c.z], 1);
        s.w = atomicAdd(&deg[c.w], 1);
        *(int4*)(seq + base) = s;
    } else {
        for (int e = base; e < E && e < base + 4; ++e)
            seq[e] = atomicAdd(&deg[col[e]], 1);
    }
}

// ---- 3-phase multi-block exclusive scan over deg[0..N) -> rowptr[0..N] ----
__global__ __launch_bounds__(256) void scan_p1_kernel(const int* __restrict__ deg,
                                                      int* __restrict__ bsum, int N) {
    int t = threadIdx.x;
    int base = blockIdx.x * 1024 + t * 4;
    int s = 0;
    #pragma unroll
    for (int k = 0; k < 4; k++) { int i = base + k; if (i < N) s += deg[i]; }
    __shared__ int red[256];
    red[t] = s;
    __syncthreads();
    for (int off = 128; off > 0; off >>= 1) {
        if (t < off) red[t] += red[t + off];
        __syncthreads();
    }
    if (t == 0) bsum[blockIdx.x] = red[0];
}

__global__ __launch_bounds__(1024) void scan_p2_kernel(int* __restrict__ bsum, int nb) {
    __shared__ int sums[1024];
    int t = threadIdx.x;
    int chunk = (nb + 1023) / 1024;
    int s0 = t * chunk, s1 = min(nb, s0 + chunk);
    int local = 0;
    for (int i = s0; i < s1; i++) local += bsum[i];
    sums[t] = local;
    __syncthreads();
    for (int off = 1; off < 1024; off <<= 1) {
        int v = (t >= off) ? sums[t - off] : 0;
        __syncthreads();
        sums[t] += v;
        __syncthreads();
    }
    int prefix = (t == 0) ? 0 : sums[t - 1];
    for (int i = s0; i < s1; i++) { int v = bsum[i]; bsum[i] = prefix; prefix += v; }
}

// Phase 3: block-local exclusive scan + bsum[b] offset -> rowptr.
// Fused: dinv[i] = 1/sqrt(deg[i]+1).
__global__ __launch_bounds__(256) void scan_p3_kernel(const int* __restrict__ deg,
                                                      const int* __restrict__ bsum,
                                                      int* __restrict__ rowptr,
                                                      float* __restrict__ dinv,
                                                      int N, int E) {
    int t = threadIdx.x;
    int base = blockIdx.x * 1024 + t * 4;
    int v[4];
    int s = 0;
    #pragma unroll
    for (int k = 0; k < 4; k++) {
        int i = base + k;
        v[k] = (i < N) ? deg[i] : 0;
        s += v[k];
    }
    __shared__ int sums[256];
    sums[t] = s;
    __syncthreads();
    for (int off = 1; off < 256; off <<= 1) {
        int u = (t >= off) ? sums[t - off] : 0;
        __syncthreads();
        sums[t] += u;
        __syncthreads();
    }
    int prefix = bsum[blockIdx.x] + ((t == 0) ? 0 : sums[t - 1]);
    #pragma unroll
    for (int k = 0; k < 4; k++) {
        int i = base + k;
        if (i < N) {
            rowptr[i] = prefix;
            dinv[i] = 1.0f / sqrtf((float)(v[k] + 1));
        }
        prefix += v[k];
    }
    if (blockIdx.x == 0 && t == 0) rowptr[N] = E;
}

// Atomic-free CSR fill x4: pos = rowptr[col] + seq.
__global__ void fill_csr_kernel(const int* __restrict__ row, const int* __restrict__ col,
                                const int* __restrict__ seq, const int* __restrict__ rowptr,
                                int* __restrict__ csr_src, int E) {
    int i = blockIdx.x * blockDim.x + threadIdx.x;
    int base = i * 4;
    if (base >= E) return;
    if (base + 4 <= E && (((size_t)col & 15) == 0)) {
        int4 c = *(const int4*)(col + base);
        int4 s = *(const int4*)(seq + base);
        int4 r = *(const int4*)(row + base);
        csr_src[rowptr[c.x] + s.x] = r.x;
        csr_src[rowptr[c.y] + s.y] = r.y;
        csr_src[rowptr[c.z] + s.z] = r.z;
        csr_src[rowptr[c.w] + s.w] = r.w;
    } else {
        for (int e = base; e < E && e < base + 4; ++e)
            csr_src[rowptr[col[e]] + seq[e]] = row[e];
    }
}

// x~ = dinv[row] * x, fp16. Row of elem group i (4 fp32) = i / (DIN/4).
__global__ void cast_f16_scaled_kernel(const float4* __restrict__ in,
                                       const float* __restrict__ dinv,
                                       ushort4* __restrict__ out, int n4) {
    int i = blockIdx.x * blockDim.x + threadIdx.x;
    if (i >= n4) return;
    float s = dinv[i >> 5];                  // DIN/4 = 32 groups per row
    float4 v = in[i];
    ushort4 o;
    o.x = f2h(v.x * s); o.y = f2h(v.y * s); o.z = f2h(v.z * s); o.w = f2h(v.w * s);
    out[i] = o;
}

// All three weight matrices -> fp16 in one launch.
// W1: 8192 float4 groups, W2/W3: 16384 each (total 40960).
__global__ void cast_weights_kernel(const float4* __restrict__ W1,
                                    const float4* __restrict__ W2,
                                    const float4* __restrict__ W3,
                                    ushort4* __restrict__ w1h,
                                    ushort4* __restrict__ w2h,
                                    ushort4* __restrict__ w3h) {
    int i = blockIdx.x * blockDim.x + threadIdx.x;
    const float4* src; ushort4* dst; int j = i;
    if (j < 8192)       { src = W1; dst = w1h; }
    else if (j < 24576) { src = W2; dst = w2h; j -= 8192; }
    else if (j < 40960) { src = W3; dst = w3h; j -= 24576; }
    else return;
    float4 v = src[j];
    ushort4 o;
    o.x = f2h(v.x); o.y = f2h(v.y); o.z = f2h(v.z); o.w = f2h(v.w);
    dst[j] = o;
}

// XCD-partitioned gather: half = blockIdx.x & 1 selects feature dims
// [half*D/2, (half+1)*D/2). L = D/8 lanes per node-half, 8B (4 fp16)/lane.
// Under round-robin block->XCD, even/odd blocks land on disjoint XCD sets,
// so each 26MB half-array is cached by 4 XCDs' L2 (16MB) -> hit rate up,
// avg miss latency down, gather BW up (MSHR-capped latency bound, R11).
// in: PRE-SCALED fp16 rows; out[n] = f2h(dinv[n] * (sum + self)).
template<int D>
__global__ __launch_bounds__(256) void agg_gather_f16_kernel(const int* __restrict__ rowptr,
                                                             const int* __restrict__ csr_src,
                                                             const float* __restrict__ dinv,
                                                             const us4* __restrict__ in,
                                                             us4* __restrict__ out, int N) {
    constexpr int L = D / 8;                 // 32 (D=256) or 16 (D=128)
    constexpr int GPB = 256 / L;             // 8 or 16 node-halves per block
    int b = blockIdx.x;
    int half = b & 1;
    int n = (b >> 1) * GPB + threadIdx.x / L;
    if (n >= N) return;
    int lane = threadIdx.x % L;
    int off = half * L + lane;               // us4 offset within the row (row = 2L us4)

    us4 sv = in[(size_t)n * (2 * L) + off];
    float4 acc = make_float4(h2f(sv.x), h2f(sv.y), h2f(sv.z), h2f(sv.w));

    int start = rowptr[n], end = rowptr[n + 1];
    for (int j0 = start; j0 < end; j0 += L) {
        int nb = end - j0; if (nb > L) nb = L;
        int src = (lane < nb) ? csr_src[j0 + lane] : 0;

        int t = 0;
        for (; t + 8 <= nb; t += 8) {
            int rr[8];
            #pragma unroll
            for (int u = 0; u < 8; ++u) rr[u] = __shfl(src, t + u, L);
            us4 vv[8];
            #pragma unroll
            for (int u = 0; u < 8; ++u) vv[u] = in[(size_t)rr[u] * (2 * L) + off];
            #pragma unroll
            for (int u = 0; u < 8; ++u) {
                acc.x += h2f(vv[u].x);
                acc.y += h2f(vv[u].y);
                acc.z += h2f(vv[u].z);
                acc.w += h2f(vv[u].w);
            }
        }
        for (; t < nb; ++t) {
            int r = __shfl(src, t, L);
            us4 v = in[(size_t)r * (2 * L) + off];
            acc.x += h2f(v.x); acc.y += h2f(v.y);
            acc.z += h2f(v.z); acc.w += h2f(v.w);
        }
    }
    float s = dinv[n];
    us4 o;
    o.x = f2h(acc.x * s); o.y = f2h(acc.y * s); o.z = f2h(acc.z * s); o.w = f2h(acc.w * s);
    out[(size_t)n * (2 * L) + off] = o;
}

// C[n][m] = sum_k A[n][k]*W[m][k]; A:[N,K] fp16, W:[256,K] fp16 (pre-cast).
// MFMA f16, fp32 accum. 128x128 tile, BK=64, 4 waves (2x2), 64x64 per wave.
// 1D grid, XCD-pairing decode: hw blocks 16g+r and 16g+r+8 (same XCD under
// round-robin) share cx -> second A-tile read hits that XCD's L2.
// SCALE: multiply output row by dinv[row] before fp16 store (h~ = dinv*relu).
template<int K, bool RELU, bool SCALE, typename OT>
__global__ __launch_bounds__(256) void gemm_nt_mfma_kernel(const unsigned short* __restrict__ A,
                                                           const unsigned short* __restrict__ Wh,
                                                           OT* __restrict__ C,
                                                           const float* __restrict__ dinv, int N) {
    __shared__ __align__(16) unsigned short As[128 * 64];
    __shared__ __align__(16) unsigned short Ws[128 * 64];
    int tid  = threadIdx.x;
    int lane = tid & 63;
    int wave = tid >> 6;
    int wr = wave >> 1, wc = wave & 1;       // wave grid 2x2

    // ---- XCD-pairing block decode
    int nwgx = (N + 127) / 128;
    int T = (2 * nwgx) & ~15;
    int b = blockIdx.x;
    int cx, cy;
    if (b < T) { cx = (b >> 4) * 8 + (b & 7); cy = (b >> 3) & 1; }
    else       { int rem = b - T; cx = (T >> 1) + (rem >> 1); cy = rem & 1; }
    int m0 = cx * 128;                       // output rows (nodes)
    int c0 = cy * 128;                       // output cols (0 or 128)

    f32x4 acc[4][4];
    #pragma unroll
    for (int i = 0; i < 4; i++)
        #pragma unroll
        for (int j = 0; j < 4; j++)
            #pragma unroll
            for (int r = 0; r < 4; r++) acc[i][j][r] = 0.0f;

    int srow  = tid >> 3;                    // 0..31: staging row within pass
    int sslot = tid & 7;                     // 16B slot within row (8 slots = 64 fp16)

    for (int k0 = 0; k0 < K; k0 += 64) {
        // ---- stage A[m0..m0+127][k0..k0+63] and W[c0..c0+127][k0..k0+63]
        #pragma unroll
        for (int q = 0; q < 4; ++q) {
            int row = q * 32 + srow;
            int byteoff = row * 128 + ((sslot ^ (row & 7)) << 4);
            int gr = m0 + row;
            if (gr >= N) gr = N - 1;         // clamp: tail rows computed, never stored
            f16x8 va = *(const f16x8*)(A + (size_t)gr * K + k0 + sslot * 8);
            *(f16x8*)((char*)As + byteoff) = va;
            int gw = c0 + row;               // always < 256
            f16x8 vw = *(const f16x8*)(Wh + (size_t)gw * K + k0 + sslot * 8);
            *(f16x8*)((char*)Ws + byteoff) = vw;
        }
        __syncthreads();

        // ---- 2 x K=32 MFMA steps over this BK=64 tile
        #pragma unroll
        for (int kk = 0; kk < 2; ++kk) {
            int slot = kk * 4 + (lane >> 4);
            f16x8 a[4], bfr[4];
            #pragma unroll
            for (int i = 0; i < 4; i++) {
                int row = wr * 64 + i * 16 + (lane & 15);
                a[i] = *(const f16x8*)((const char*)As + row * 128 + ((slot ^ (row & 7)) << 4));
            }
            #pragma unroll
            for (int j = 0; j < 4; j++) {
                int row = wc * 64 + j * 16 + (lane & 15);
                bfr[j] = *(const f16x8*)((const char*)Ws + row * 128 + ((slot ^ (row & 7)) << 4));
            }
            #pragma unroll
            for (int i = 0; i < 4; i++)
                #pragma unroll
                for (int j = 0; j < 4; j++)
                    acc[i][j] = __builtin_amdgcn_mfma_f32_16x16x32_f16(a[i], bfr[j], acc[i][j], 0, 0, 0);
        }
        __syncthreads();
    }

    // ---- epilogue: D lane map (verified m89): col = lane&15, row = (lane>>4)*4 + r
    int r4 = (lane >> 4) * 4;
    int cn = lane & 15;
    #pragma unroll
    for (int i = 0; i < 4; i++) {
        #pragma unroll
        for (int r = 0; r < 4; r++) {
            int g_r = m0 + wr * 64 + i * 16 + r4 + r;
            if (g_r >= N) continue;
            float dv = SCALE ? dinv[g_r] : 1.0f;
            #pragma unroll
            for (int j = 0; j < 4; j++) {
                float v = acc[i][j][r];
                if (RELU) v = fmaxf(v, 0.f);
                if (SCALE) v *= dv;
                int col = c0 + wc * 64 + j * 16 + cn;
                if constexpr (sizeof(OT) == 4) {
                    ((float*)C)[(size_t)g_r * DH + col] = v;
                } else {
                    ((unsigned short*)C)[(size_t)g_r * DH + col] = f2h(v);
                }
            }
        }
    }
}

extern "C" void kernel_launch(void* const* d_in, const int* in_sizes, int n_in,
                              void* d_out, int out_size, void* d_ws, size_t ws_size,
                              hipStream_t stream) {
    const float* x  = (const float*)d_in[0];
    const int*   ei = (const int*)d_in[1];
    const float* W1 = (const float*)d_in[2];
    const float* W2 = (const float*)d_in[3];
    const float* W3 = (const float*)d_in[4];
    float* out = (float*)d_out;

    int N = in_sizes[0] / DIN;
    int E = in_sizes[1] / 2;
    const int* row = ei;         // sources
    const int* col = ei + E;     // targets (aggregation)

    char* ws = (char*)d_ws;
    int*   deg     = (int*)ws;                      // N ints
    float* dinv    = (float*)(ws + 400000);         // N floats
    int*   rowptr  = (int*)(ws + 800000);           // N+1 ints
    int*   csr_src = (int*)(ws + 1200016);          // E ints
    int*   seq     = (int*)(ws + 7600016);          // E ints
    unsigned short* bufA = (unsigned short*)(ws + 14000128);  // N*256 fp16 agg out (A operand)
    unsigned short* w1h  = (unsigned short*)(ws + 65200128);  // 256*128 fp16
    unsigned short* w2h  = (unsigned short*)(ws + 65265664);  // 256*256 fp16
    unsigned short* w3h  = (unsigned short*)(ws + 65396736);  // 256*256 fp16
    int*   bsum    = (int*)(ws + 65527808);         // ~(N/1024)+1 ints, scan block sums

    // fp16 staging for gather inputs lives inside d_out (dead/overwritten):
    // x~ (N*128, 25.6MB) is dead before GEMM1 writes h~ (N*256 fp16, 51.2MB)
    // over it; GEMM3 fully overwrites d_out with the fp32 result.
    unsigned short* hb = (unsigned short*)d_out;

    dim3 b256(256);
    int nb = (N + 1023) / 1024;                     // scan blocks (98 @ N=100K)

    // CSR build: deg+seq -> rowptr (3-phase scan, dinv fused) -> atomic-free fill
    zero_int_kernel<<<dim3((N + 255) / 256), b256, 0, stream>>>(deg, N);
    count_deg_kernel<<<dim3(((E + 3) / 4 + 255) / 256), b256, 0, stream>>>(col, E, deg, seq);
    scan_p1_kernel<<<dim3(nb), b256, 0, stream>>>(deg, bsum, N);
    scan_p2_kernel<<<dim3(1), dim3(1024), 0, stream>>>(bsum, nb);
    scan_p3_kernel<<<dim3(nb), b256, 0, stream>>>(deg, bsum, rowptr, dinv, N, E);
    fill_csr_kernel<<<dim3(((E + 3) / 4 + 255) / 256), b256, 0, stream>>>(
        row, col, seq, rowptr, csr_src, E);

    // x~ = dinv*x (needs dinv from scan_p3); all weights in one launch
    cast_f16_scaled_kernel<<<dim3((N * (DIN / 4) + 255) / 256), b256, 0, stream>>>(
        (const float4*)x, dinv, (ushort4*)hb, N * (DIN / 4));
    cast_weights_kernel<<<dim3(160), b256, 0, stream>>>(
        (const float4*)W1, (const float4*)W2, (const float4*)W3,
        (ushort4*)w1h, (ushort4*)w2h, (ushort4*)w3h);

    int nwg = 2 * ((N + 127) / 128);

    // gather grids: 2 halves x ceil(N/GPB) node-blocks (GPB = 256/(D/8))
    int g128 = 2 * ((N + 15) / 16);   // D=128: GPB=16
    int g256 = 2 * ((N + 7) / 8);     // D=256: GPB=8

    // ---- Layer 1: s = dinv*(sum x~); h1~ = dinv*f16(relu(s @ W1^T))
    agg_gather_f16_kernel<DIN><<<dim3(g128), b256, 0, stream>>>(
        rowptr, csr_src, dinv, (const us4*)hb, (us4*)bufA, N);
    gemm_nt_mfma_kernel<DIN, true, true, unsigned short><<<dim3(nwg), b256, 0, stream>>>(
        bufA, w1h, hb, dinv, N);

    // ---- Layer 2: s = dinv*(sum h1~); h2~ = dinv*f16(relu(s @ W2^T))
    agg_gather_f16_kernel<DH><<<dim3(g256), b256, 0, stream>>>(
        rowptr, csr_src, dinv, (const us4*)hb, (us4*)bufA, N);
    gemm_nt_mfma_kernel<DH, true, true, unsigned short><<<dim3(nwg), b256, 0, stream>>>(
        bufA, w2h, hb, dinv, N);

    // ---- Layer 3: s = dinv*(sum h2~); out = s @ W3^T (fp32, full overwrite)
    agg_gather_f16_kernel<DH><<<dim3(g256), b256, 0, stream>>>(
        rowptr, csr_src, dinv, (const us4*)hb, (us4*)bufA, N);
    gemm_nt_mfma_kernel<DH, false, false, float><<<dim3(nwg), b256, 0, stream>>>(
        bufA, w3h, out, dinv, N);
}

// Round 9
// 629.475 us; speedup vs baseline: 1.1922x; 1.0067x over previous
//
#include <hip/hip_runtime.h>

// ---------------------------------------------------------------------------
// GCN 3-layer forward on MI355X — Round 13: GEMM prefetch pipeline.
// R12 post-mortem: gather at ~112us is within ~10% of its MSHR/latency floor
// (5 experiments: unroll/wide/nt/XCD-split bound it). Remaining targets are
// sub-top-5: GEMMs + launch overhead.
//  (1) GEMM K-loop: T14 async-stage. Prologue-load tile0 to regs; per iter:
//      [bar] -> ds_write(t) -> issue global loads(t+1) -> bar -> MFMA(t).
//      Tile fetch (32KB A+W) now flies under MFMA instead of serializing.
//  (2) zero_int kernel -> hipMemsetAsync (one fewer dispatch).
// Gather (R12 XCD half-split), scan, atomic-free CSR, folded norm unchanged.
// ---------------------------------------------------------------------------

constexpr int DIN = 128;
constexpr int DH  = 256;

typedef _Float16 f16x8 __attribute__((ext_vector_type(8)));
typedef float    f32x4 __attribute__((ext_vector_type(4)));
typedef unsigned short us4 __attribute__((ext_vector_type(4)));

__device__ __forceinline__ float h2f(unsigned short u) {
    _Float16 h;
    __builtin_memcpy(&h, &u, 2);
    return (float)h;
}
__device__ __forceinline__ unsigned short f2h(float f) {
    _Float16 h = (_Float16)f;
    unsigned short u;
    __builtin_memcpy(&u, &h, 2);
    return u;
}

// Degree count x4; atomic return value = within-node slot -> seq[e].
__global__ void count_deg_kernel(const int* __restrict__ col, int E,
                                 int* __restrict__ deg, int* __restrict__ seq) {
    int i = blockIdx.x * blockDim.x + threadIdx.x;
    int base = i * 4;
    if (base >= E) return;
    if (base + 4 <= E && (((size_t)col & 15) == 0)) {
        int4 c = *(const int4*)(col + base);
        int4 s;
        s.x = atomicAdd(&deg[c.x], 1);
        s.y = atomicAdd(&deg[c.y], 1);
        s.z = atomicAdd(&deg[c.z], 1);
        s.w = atomicAdd(&deg[c.w], 1);
        *(int4*)(seq + base) = s;
    } else {
        for (int e = base; e < E && e < base + 4; ++e)
            seq[e] = atomicAdd(&deg[col[e]], 1);
    }
}

// ---- 3-phase multi-block exclusive scan over deg[0..N) -> rowptr[0..N] ----
__global__ __launch_bounds__(256) void scan_p1_kernel(const int* __restrict__ deg,
                                                      int* __restrict__ bsum, int N) {
    int t = threadIdx.x;
    int base = blockIdx.x * 1024 + t * 4;
    int s = 0;
    #pragma unroll
    for (int k = 0; k < 4; k++) { int i = base + k; if (i < N) s += deg[i]; }
    __shared__ int red[256];
    red[t] = s;
    __syncthreads();
    for (int off = 128; off > 0; off >>= 1) {
        if (t < off) red[t] += red[t + off];
        __syncthreads();
    }
    if (t == 0) bsum[blockIdx.x] = red[0];
}

__global__ __launch_bounds__(1024) void scan_p2_kernel(int* __restrict__ bsum, int nb) {
    __shared__ int sums[1024];
    int t = threadIdx.x;
    int chunk = (nb + 1023) / 1024;
    int s0 = t * chunk, s1 = min(nb, s0 + chunk);
    int local = 0;
    for (int i = s0; i < s1; i++) local += bsum[i];
    sums[t] = local;
    __syncthreads();
    for (int off = 1; off < 1024; off <<= 1) {
        int v = (t >= off) ? sums[t - off] : 0;
        __syncthreads();
        sums[t] += v;
        __syncthreads();
    }
    int prefix = (t == 0) ? 0 : sums[t - 1];
    for (int i = s0; i < s1; i++) { int v = bsum[i]; bsum[i] = prefix; prefix += v; }
}

// Phase 3: block-local exclusive scan + bsum[b] offset -> rowptr.
// Fused: dinv[i] = 1/sqrt(deg[i]+1).
__global__ __launch_bounds__(256) void scan_p3_kernel(const int* __restrict__ deg,
                                                      const int* __restrict__ bsum,
                                                      int* __restrict__ rowptr,
                                                      float* __restrict__ dinv,
                                                      int N, int E) {
    int t = threadIdx.x;
    int base = blockIdx.x * 1024 + t * 4;
    int v[4];
    int s = 0;
    #pragma unroll
    for (int k = 0; k < 4; k++) {
        int i = base + k;
        v[k] = (i < N) ? deg[i] : 0;
        s += v[k];
    }
    __shared__ int sums[256];
    sums[t] = s;
    __syncthreads();
    for (int off = 1; off < 256; off <<= 1) {
        int u = (t >= off) ? sums[t - off] : 0;
        __syncthreads();
        sums[t] += u;
        __syncthreads();
    }
    int prefix = bsum[blockIdx.x] + ((t == 0) ? 0 : sums[t - 1]);
    #pragma unroll
    for (int k = 0; k < 4; k++) {
        int i = base + k;
        if (i < N) {
            rowptr[i] = prefix;
            dinv[i] = 1.0f / sqrtf((float)(v[k] + 1));
        }
        prefix += v[k];
    }
    if (blockIdx.x == 0 && t == 0) rowptr[N] = E;
}

// Atomic-free CSR fill x4: pos = rowptr[col] + seq.
__global__ void fill_csr_kernel(const int* __restrict__ row, const int* __restrict__ col,
                                const int* __restrict__ seq, const int* __restrict__ rowptr,
                                int* __restrict__ csr_src, int E) {
    int i = blockIdx.x * blockDim.x + threadIdx.x;
    int base = i * 4;
    if (base >= E) return;
    if (base + 4 <= E && (((size_t)col & 15) == 0)) {
        int4 c = *(const int4*)(col + base);
        int4 s = *(const int4*)(seq + base);
        int4 r = *(const int4*)(row + base);
        csr_src[rowptr[c.x] + s.x] = r.x;
        csr_src[rowptr[c.y] + s.y] = r.y;
        csr_src[rowptr[c.z] + s.z] = r.z;
        csr_src[rowptr[c.w] + s.w] = r.w;
    } else {
        for (int e = base; e < E && e < base + 4; ++e)
            csr_src[rowptr[col[e]] + seq[e]] = row[e];
    }
}

// x~ = dinv[row] * x, fp16. Row of elem group i (4 fp32) = i / (DIN/4).
__global__ void cast_f16_scaled_kernel(const float4* __restrict__ in,
                                       const float* __restrict__ dinv,
                                       ushort4* __restrict__ out, int n4) {
    int i = blockIdx.x * blockDim.x + threadIdx.x;
    if (i >= n4) return;
    float s = dinv[i >> 5];                  // DIN/4 = 32 groups per row
    float4 v = in[i];
    ushort4 o;
    o.x = f2h(v.x * s); o.y = f2h(v.y * s); o.z = f2h(v.z * s); o.w = f2h(v.w * s);
    out[i] = o;
}

// All three weight matrices -> fp16 in one launch.
// W1: 8192 float4 groups, W2/W3: 16384 each (total 40960).
__global__ void cast_weights_kernel(const float4* __restrict__ W1,
                                    const float4* __restrict__ W2,
                                    const float4* __restrict__ W3,
                                    ushort4* __restrict__ w1h,
                                    ushort4* __restrict__ w2h,
                                    ushort4* __restrict__ w3h) {
    int i = blockIdx.x * blockDim.x + threadIdx.x;
    const float4* src; ushort4* dst; int j = i;
    if (j < 8192)       { src = W1; dst = w1h; }
    else if (j < 24576) { src = W2; dst = w2h; j -= 8192; }
    else if (j < 40960) { src = W3; dst = w3h; j -= 24576; }
    else return;
    float4 v = src[j];
    ushort4 o;
    o.x = f2h(v.x); o.y = f2h(v.y); o.z = f2h(v.z); o.w = f2h(v.w);
    dst[j] = o;
}

// XCD-partitioned gather: half = blockIdx.x & 1 selects feature dims
// [half*D/2, (half+1)*D/2). L = D/8 lanes per node-half, 8B (4 fp16)/lane.
// Even/odd blocks land on disjoint XCD sets under round-robin -> each half
// array cached by 4 XCDs' L2 -> higher hit rate, lower avg latency (R12).
// in: PRE-SCALED fp16 rows; out[n] = f2h(dinv[n] * (sum + self)).
template<int D>
__global__ __launch_bounds__(256) void agg_gather_f16_kernel(const int* __restrict__ rowptr,
                                                             const int* __restrict__ csr_src,
                                                             const float* __restrict__ dinv,
                                                             const us4* __restrict__ in,
                                                             us4* __restrict__ out, int N) {
    constexpr int L = D / 8;                 // 32 (D=256) or 16 (D=128)
    constexpr int GPB = 256 / L;             // 8 or 16 node-halves per block
    int b = blockIdx.x;
    int half = b & 1;
    int n = (b >> 1) * GPB + threadIdx.x / L;
    if (n >= N) return;
    int lane = threadIdx.x % L;
    int off = half * L + lane;               // us4 offset within the row (row = 2L us4)

    us4 sv = in[(size_t)n * (2 * L) + off];
    float4 acc = make_float4(h2f(sv.x), h2f(sv.y), h2f(sv.z), h2f(sv.w));

    int start = rowptr[n], end = rowptr[n + 1];
    for (int j0 = start; j0 < end; j0 += L) {
        int nb = end - j0; if (nb > L) nb = L;
        int src = (lane < nb) ? csr_src[j0 + lane] : 0;

        int t = 0;
        for (; t + 8 <= nb; t += 8) {
            int rr[8];
            #pragma unroll
            for (int u = 0; u < 8; ++u) rr[u] = __shfl(src, t + u, L);
            us4 vv[8];
            #pragma unroll
            for (int u = 0; u < 8; ++u) vv[u] = in[(size_t)rr[u] * (2 * L) + off];
            #pragma unroll
            for (int u = 0; u < 8; ++u) {
                acc.x += h2f(vv[u].x);
                acc.y += h2f(vv[u].y);
                acc.z += h2f(vv[u].z);
                acc.w += h2f(vv[u].w);
            }
        }
        for (; t < nb; ++t) {
            int r = __shfl(src, t, L);
            us4 v = in[(size_t)r * (2 * L) + off];
            acc.x += h2f(v.x); acc.y += h2f(v.y);
            acc.z += h2f(v.z); acc.w += h2f(v.w);
        }
    }
    float s = dinv[n];
    us4 o;
    o.x = f2h(acc.x * s); o.y = f2h(acc.y * s); o.z = f2h(acc.z * s); o.w = f2h(acc.w * s);
    out[(size_t)n * (2 * L) + off] = o;
}

// C[n][m] = sum_k A[n][k]*W[m][k]; A:[N,K] fp16, W:[256,K] fp16 (pre-cast).
// MFMA f16, fp32 accum. 128x128 tile, BK=64, 4 waves (2x2), 64x64 per wave.
// T14 async-stage: tile t+1 global loads issued BEFORE MFMA(t) -> fetch
// hides under compute. 1D grid with XCD-pairing decode (R8).
// SCALE: multiply output row by dinv[row] before fp16 store (h~ = dinv*relu).
template<int K, bool RELU, bool SCALE, typename OT>
__global__ __launch_bounds__(256) void gemm_nt_mfma_kernel(const unsigned short* __restrict__ A,
                                                           const unsigned short* __restrict__ Wh,
                                                           OT* __restrict__ C,
                                                           const float* __restrict__ dinv, int N) {
    __shared__ __align__(16) unsigned short As[128 * 64];
    __shared__ __align__(16) unsigned short Ws[128 * 64];
    int tid  = threadIdx.x;
    int lane = tid & 63;
    int wave = tid >> 6;
    int wr = wave >> 1, wc = wave & 1;       // wave grid 2x2

    // ---- XCD-pairing block decode
    int nwgx = (N + 127) / 128;
    int T = (2 * nwgx) & ~15;
    int b = blockIdx.x;
    int cx, cy;
    if (b < T) { cx = (b >> 4) * 8 + (b & 7); cy = (b >> 3) & 1; }
    else       { int rem = b - T; cx = (T >> 1) + (rem >> 1); cy = rem & 1; }
    int m0 = cx * 128;                       // output rows (nodes)
    int c0 = cy * 128;                       // output cols (0 or 128)

    f32x4 acc[4][4];
    #pragma unroll
    for (int i = 0; i < 4; i++)
        #pragma unroll
        for (int j = 0; j < 4; j++)
            #pragma unroll
            for (int r = 0; r < 4; r++) acc[i][j][r] = 0.0f;

    int srow  = tid >> 3;                    // 0..31: staging row within pass
    int sslot = tid & 7;                     // 16B slot within row (8 slots = 64 fp16)

    constexpr int NT = K / 64;               // 2 (K=128) or 4 (K=256)
    f16x8 pva[4], pvw[4];

    // ---- prologue: load tile 0 into regs
    #pragma unroll
    for (int q = 0; q < 4; ++q) {
        int row = q * 32 + srow;
        int gr = m0 + row;
        if (gr >= N) gr = N - 1;             // clamp: tail rows computed, never stored
        pva[q] = *(const f16x8*)(A + (size_t)gr * K + sslot * 8);
        pvw[q] = *(const f16x8*)(Wh + (size_t)(c0 + row) * K + sslot * 8);
    }

    for (int t = 0; t < NT; ++t) {
        if (t) __syncthreads();              // MFMA(t-1) done reading LDS

        // ---- ds_write staged tile t
        #pragma unroll
        for (int q = 0; q < 4; ++q) {
            int row = q * 32 + srow;
            int byteoff = row * 128 + ((sslot ^ (row & 7)) << 4);
            *(f16x8*)((char*)As + byteoff) = pva[q];
            *(f16x8*)((char*)Ws + byteoff) = pvw[q];
        }

        // ---- issue tile t+1 loads (fly under MFMA below)
        if (t + 1 < NT) {
            int k0 = (t + 1) * 64;
            #pragma unroll
            for (int q = 0; q < 4; ++q) {
                int row = q * 32 + srow;
                int gr = m0 + row;
                if (gr >= N) gr = N - 1;
                pva[q] = *(const f16x8*)(A + (size_t)gr * K + k0 + sslot * 8);
                pvw[q] = *(const f16x8*)(Wh + (size_t)(c0 + row) * K + k0 + sslot * 8);
            }
        }
        __syncthreads();

        // ---- 2 x K=32 MFMA steps over this BK=64 tile
        #pragma unroll
        for (int kk = 0; kk < 2; ++kk) {
            int slot = kk * 4 + (lane >> 4);
            f16x8 a[4], bfr[4];
            #pragma unroll
            for (int i = 0; i < 4; i++) {
                int row = wr * 64 + i * 16 + (lane & 15);
                a[i] = *(const f16x8*)((const char*)As + row * 128 + ((slot ^ (row & 7)) << 4));
            }
            #pragma unroll
            for (int j = 0; j < 4; j++) {
                int row = wc * 64 + j * 16 + (lane & 15);
                bfr[j] = *(const f16x8*)((const char*)Ws + row * 128 + ((slot ^ (row & 7)) << 4));
            }
            #pragma unroll
            for (int i = 0; i < 4; i++)
                #pragma unroll
                for (int j = 0; j < 4; j++)
                    acc[i][j] = __builtin_amdgcn_mfma_f32_16x16x32_f16(a[i], bfr[j], acc[i][j], 0, 0, 0);
        }
    }

    // ---- epilogue: D lane map (verified m89): col = lane&15, row = (lane>>4)*4 + r
    int r4 = (lane >> 4) * 4;
    int cn = lane & 15;
    #pragma unroll
    for (int i = 0; i < 4; i++) {
        #pragma unroll
        for (int r = 0; r < 4; r++) {
            int g_r = m0 + wr * 64 + i * 16 + r4 + r;
            if (g_r >= N) continue;
            float dv = SCALE ? dinv[g_r] : 1.0f;
            #pragma unroll
            for (int j = 0; j < 4; j++) {
                float v = acc[i][j][r];
                if (RELU) v = fmaxf(v, 0.f);
                if (SCALE) v *= dv;
                int col = c0 + wc * 64 + j * 16 + cn;
                if constexpr (sizeof(OT) == 4) {
                    ((float*)C)[(size_t)g_r * DH + col] = v;
                } else {
                    ((unsigned short*)C)[(size_t)g_r * DH + col] = f2h(v);
                }
            }
        }
    }
}

extern "C" void kernel_launch(void* const* d_in, const int* in_sizes, int n_in,
                              void* d_out, int out_size, void* d_ws, size_t ws_size,
                              hipStream_t stream) {
    const float* x  = (const float*)d_in[0];
    const int*   ei = (const int*)d_in[1];
    const float* W1 = (const float*)d_in[2];
    const float* W2 = (const float*)d_in[3];
    const float* W3 = (const float*)d_in[4];
    float* out = (float*)d_out;

    int N = in_sizes[0] / DIN;
    int E = in_sizes[1] / 2;
    const int* row = ei;         // sources
    const int* col = ei + E;     // targets (aggregation)

    char* ws = (char*)d_ws;
    int*   deg     = (int*)ws;                      // N ints
    float* dinv    = (float*)(ws + 400000);         // N floats
    int*   rowptr  = (int*)(ws + 800000);           // N+1 ints
    int*   csr_src = (int*)(ws + 1200016);          // E ints
    int*   seq     = (int*)(ws + 7600016);          // E ints
    unsigned short* bufA = (unsigned short*)(ws + 14000128);  // N*256 fp16 agg out (A operand)
    unsigned short* w1h  = (unsigned short*)(ws + 65200128);  // 256*128 fp16
    unsigned short* w2h  = (unsigned short*)(ws + 65265664);  // 256*256 fp16
    unsigned short* w3h  = (unsigned short*)(ws + 65396736);  // 256*256 fp16
    int*   bsum    = (int*)(ws + 65527808);         // ~(N/1024)+1 ints, scan block sums

    // fp16 staging for gather inputs lives inside d_out (dead/overwritten):
    // x~ (N*128, 25.6MB) is dead before GEMM1 writes h~ (N*256 fp16, 51.2MB)
    // over it; GEMM3 fully overwrites d_out with the fp32 result.
    unsigned short* hb = (unsigned short*)d_out;

    dim3 b256(256);
    int nb = (N + 1023) / 1024;                     // scan blocks (98 @ N=100K)

    // CSR build: deg+seq -> rowptr (3-phase scan, dinv fused) -> atomic-free fill
    hipMemsetAsync(deg, 0, (size_t)N * sizeof(int), stream);
    count_deg_kernel<<<dim3(((E + 3) / 4 + 255) / 256), b256, 0, stream>>>(col, E, deg, seq);
    scan_p1_kernel<<<dim3(nb), b256, 0, stream>>>(deg, bsum, N);
    scan_p2_kernel<<<dim3(1), dim3(1024), 0, stream>>>(bsum, nb);
    scan_p3_kernel<<<dim3(nb), b256, 0, stream>>>(deg, bsum, rowptr, dinv, N, E);
    fill_csr_kernel<<<dim3(((E + 3) / 4 + 255) / 256), b256, 0, stream>>>(
        row, col, seq, rowptr, csr_src, E);

    // x~ = dinv*x (needs dinv from scan_p3); all weights in one launch
    cast_f16_scaled_kernel<<<dim3((N * (DIN / 4) + 255) / 256), b256, 0, stream>>>(
        (const float4*)x, dinv, (ushort4*)hb, N * (DIN / 4));
    cast_weights_kernel<<<dim3(160), b256, 0, stream>>>(
        (const float4*)W1, (const float4*)W2, (const float4*)W3,
        (ushort4*)w1h, (ushort4*)w2h, (ushort4*)w3h);

    int nwg = 2 * ((N + 127) / 128);

    // gather grids: 2 halves x ceil(N/GPB) node-blocks (GPB = 256/(D/8))
    int g128 = 2 * ((N + 15) / 16);   // D=128: GPB=16
    int g256 = 2 * ((N + 7) / 8);     // D=256: GPB=8

    // ---- Layer 1: s = dinv*(sum x~); h1~ = dinv*f16(relu(s @ W1^T))
    agg_gather_f16_kernel<DIN><<<dim3(g128), b256, 0, stream>>>(
        rowptr, csr_src, dinv, (const us4*)hb, (us4*)bufA, N);
    gemm_nt_mfma_kernel<DIN, true, true, unsigned short><<<dim3(nwg), b256, 0, stream>>>(
        bufA, w1h, hb, dinv, N);

    // ---- Layer 2: s = dinv*(sum h1~); h2~ = dinv*f16(relu(s @ W2^T))
    agg_gather_f16_kernel<DH><<<dim3(g256), b256, 0, stream>>>(
        rowptr, csr_src, dinv, (const us4*)hb, (us4*)bufA, N);
    gemm_nt_mfma_kernel<DH, true, true, unsigned short><<<dim3(nwg), b256, 0, stream>>>(
        bufA, w2h, hb, dinv, N);

    // ---- Layer 3: s = dinv*(sum h2~); out = s @ W3^T (fp32, full overwrite)
    agg_gather_f16_kernel<DH><<<dim3(g256), b256, 0, stream>>>(
        rowptr, csr_src, dinv, (const us4*)hb, (us4*)bufA, N);
    gemm_nt_mfma_kernel<DH, false, false, float><<<dim3(nwg), b256, 0, stream>>>(
        bufA, w3h, out, dinv, N);
}